// Round 10
// baseline (39.116 us; speedup 1.0000x reference)
//
#include <hip/hip_runtime.h>
#include <cstddef>

// ---------------------------------------------------------------------------
// TCFPEmbedding: out[i,:] = fake_quantize_tcfp12(weight[indices[i], :])
//   per 64-elem block: scale = max(min(absmax, 3*std), 1e-12)
//   q    = clip(rint(x/scale*127), -127, 127); main = q*(scale/127)
//   res  = x - main; rmax = max(absmax(res), 1e-12)
//   idx  = searchsorted(NF4_MIDPOINTS, res/rmax, side='left')  (strict mid < rn)
//   out  = main + NF4_LEVELS[idx]*rmax
// R10: persistent grid-stride waves + 1-deep prefetch. 8192 waves, each loops
// 12 strips (strip = 256 cols of one row; lane -> float4; 16-lane group ==
// one 64-elem quant block). Next strip's index+row loads are issued BEFORE
// computing the current strip, hiding gather latency under the ~500-cyc
// compute chain. LUT build amortized over 12 strips/wave.
// Per-element math identical to R8: DPP row_ror reductions (pure VALU),
// 64-bin packed NF4 LUT (8B entries: exact f32 midpoint + i8 levels),
// nontemporal stores (write-once stream; keep weight in L2/L3).
// ---------------------------------------------------------------------------

typedef float fx4 __attribute__((ext_vector_type(4)));
typedef int   ix2 __attribute__((ext_vector_type(2)));

namespace {

constexpr float kL[16] = {
    -1.0f, -0.6961928009986877f, -0.5250730514526367f, -0.39491748809814453f,
    -0.28444138169288635f, -0.18477343022823334f, -0.09105003625154495f, 0.0f,
    0.07958029955625534f, 0.16093020141124725f, 0.24611230194568634f,
    0.33791524171829224f, 0.44070982933044434f, 0.5626170039176941f,
    0.8481764793395996f, 1.0f};

} // namespace

__device__ __constant__ float kNF4Levels[16] = {
    -1.0f, -0.6961928009986877f, -0.5250730514526367f, -0.39491748809814453f,
    -0.28444138169288635f, -0.18477343022823334f, -0.09105003625154495f, 0.0f,
    0.07958029955625534f, 0.16093020141124725f, 0.24611230194568634f,
    0.33791524171829224f, 0.44070982933044434f, 0.5626170039176941f,
    0.8481764793395996f, 1.0f};

// DPP row rotate (within 16-lane row): ror1=0x121 ror2=0x122 ror4=0x124 ror8=0x128
template <int CTRL>
__device__ __forceinline__ float dpp_rorf(float v) {
  return __builtin_bit_cast(
      float, __builtin_amdgcn_update_dpp(0, __builtin_bit_cast(int, v), CTRL,
                                         0xF, 0xF, true));
}

__device__ __forceinline__ void build_bins(ix2* bins, int tid) {
  if (tid < 64) {
    const int j = tid;
    const float L = j * 0.03125f - 1.0f;             // bin left edge (exact)
    int base = 0;
#pragma unroll
    for (int k = 0; k < 15; ++k) {
      const float mid = (kL[k] + kL[k + 1]) * 0.5f;  // compile-time f32
      base += (mid < L) ? 1 : 0;                     // count(mid < L)
    }
    float mstar = 2.0f;                              // sentinel: never < rn
    float lo = kNF4Levels[base];
    float hi = lo;
    if (base < 15) {
      float mb = 0.0f;
#pragma unroll
      for (int k = 0; k < 15; ++k)
        if (k == base) mb = (kL[k] + kL[k + 1]) * 0.5f;
      if (mb < L + 0.03125f) {                       // midpoint inside bin
        mstar = mb;
        hi = kNF4Levels[base + 1];
      }
    }
    const int lo_i = (int)rintf(lo * 127.0f);        // [-127,127]
    const int hi_i = (int)rintf(hi * 127.0f);
    ix2 b;
    b.x = __builtin_bit_cast(int, mstar);
    b.y = (lo_i & 0xff) | ((hi_i & 0xff) << 8);
    bins[j] = b;
  }
}

// Fake-quantize this thread's 4 elems (one 64-elem quant block per 16-lane
// group). `bins` = LDS 64-entry packed NF4 bin table (8B/entry).
__device__ __forceinline__ fx4 tcfp12_quantize(fx4 x, const ix2* bins) {
  // ---- block stats via DPP rotate-reduce over the 16-lane row ----
  float am = fmaxf(fmaxf(fabsf(x.x), fabsf(x.y)), fmaxf(fabsf(x.z), fabsf(x.w)));
  float s  = (x.x + x.y) + (x.z + x.w);
  float ss = fmaf(x.x, x.x, fmaf(x.y, x.y, fmaf(x.z, x.z, x.w * x.w)));
  am = fmaxf(am, dpp_rorf<0x121>(am)); s += dpp_rorf<0x121>(s); ss += dpp_rorf<0x121>(ss);
  am = fmaxf(am, dpp_rorf<0x122>(am)); s += dpp_rorf<0x122>(s); ss += dpp_rorf<0x122>(ss);
  am = fmaxf(am, dpp_rorf<0x124>(am)); s += dpp_rorf<0x124>(s); ss += dpp_rorf<0x124>(ss);
  am = fmaxf(am, dpp_rorf<0x128>(am)); s += dpp_rorf<0x128>(s); ss += dpp_rorf<0x128>(ss);

  const float mean  = s * 0.015625f;                       // /64
  const float var   = fmaxf(ss * 0.015625f - mean * mean, 0.0f);
  const float scale = fmaxf(fminf(am, 3.0f * sqrtf(var)), 1e-12f);
  const float to_q   = 127.0f / scale;  // precise IEEE div, once per block
  const float from_q = scale / 127.0f;

  // ---- int8 main component (med3 = clamp) ----
  const float q0 = __builtin_amdgcn_fmed3f(rintf(x.x * to_q), -127.0f, 127.0f);
  const float q1 = __builtin_amdgcn_fmed3f(rintf(x.y * to_q), -127.0f, 127.0f);
  const float q2 = __builtin_amdgcn_fmed3f(rintf(x.z * to_q), -127.0f, 127.0f);
  const float q3 = __builtin_amdgcn_fmed3f(rintf(x.w * to_q), -127.0f, 127.0f);
  const float m0 = q0 * from_q, m1 = q1 * from_q, m2 = q2 * from_q, m3 = q3 * from_q;
  const float r0 = x.x - m0, r1 = x.y - m1, r2 = x.z - m2, r3 = x.w - m3;

  // ---- residual absmax over the block (DPP rotate-reduce) ----
  float rm = fmaxf(fmaxf(fabsf(r0), fabsf(r1)), fmaxf(fabsf(r2), fabsf(r3)));
  rm = fmaxf(rm, dpp_rorf<0x121>(rm));
  rm = fmaxf(rm, dpp_rorf<0x122>(rm));
  rm = fmaxf(rm, dpp_rorf<0x124>(rm));
  rm = fmaxf(rm, dpp_rorf<0x128>(rm));
  rm = fmaxf(rm, 1e-12f);
  const float invr = 1.0f / rm;            // precise, once per block
  const float rmq  = rm * (1.0f / 127.0f); // level = i8/127 folded scale

  // ---- NF4 residual via 64-bin packed LUT + combine ----
  fx4 o;
#pragma unroll
  for (int e = 0; e < 4; ++e) {
    const float r  = (e == 0) ? r0 : (e == 1) ? r1 : (e == 2) ? r2 : r3;
    const float mn = (e == 0) ? m0 : (e == 1) ? m1 : (e == 2) ? m2 : m3;
    const float rn = r * invr;                       // in [-1, 1]
    const float t  = fmaf(rn, 32.0f, 32.0f);         // >= 0 exactly at rn=-1
    int j = (int)t;                                  // trunc == floor (t>=0)
    j = (j > 63) ? 63 : j;                           // rn==1 -> bin 63
    const ix2 b = bins[j];                           // {mstar_f32, lo_i8|hi_i8<<8}
    const float mstar = __builtin_bit_cast(float, b.x);
    const int   off   = (rn > mstar) ? 8 : 0;        // strict: side='left'
    const int   li    = (int)((signed char)((b.y >> off) & 0xff));
    const float oe = fmaf((float)li, rmq, mn);
    if (e == 0) o.x = oe; else if (e == 1) o.y = oe;
    else if (e == 2) o.z = oe; else o.w = oe;
  }
  return o;
}

// Persistent-wave kernel, specialized for dim == 768 (3 strips of 256/row).
__global__ void __launch_bounds__(256)
tcfp_embedding_768_persist(const int* __restrict__ indices,
                           const float* __restrict__ weight,
                           float* __restrict__ out,
                           int nstrips, int wave_stride) {
  __shared__ ix2 bins[64];  // 512B packed NF4 bin table
  const int tid = threadIdx.x;
  build_bins(bins, tid);
  __syncthreads();

  const int lane    = tid & 63;
  const int col_off = lane * 4;
  // wave id is uniform; readfirstlane lets the compiler scalarize row math
  int s = __builtin_amdgcn_readfirstlane(blockIdx.x * 4 + (tid >> 6));
  if (s >= nstrips) return;

  // ---- prologue: load strip s ----
  int row = s / 3;
  int col = (s - row * 3) * 256 + col_off;
  fx4 x = *reinterpret_cast<const fx4*>(
      weight + (size_t)indices[row] * 768 + col);
  size_t ooff = (size_t)row * 768 + col;

  for (;;) {
    const int s_next = s + wave_stride;
    const bool more  = s_next < nstrips;
    fx4 xn;
    size_t ooff_n = 0;
    if (more) {
      // prefetch next strip: issued BEFORE current strip's compute chain
      const int rn = s_next / 3;
      const int cn = (s_next - rn * 3) * 256 + col_off;
      xn = *reinterpret_cast<const fx4*>(
          weight + (size_t)indices[rn] * 768 + cn);
      ooff_n = (size_t)rn * 768 + cn;
    }

    const fx4 o = tcfp12_quantize(x, bins);
    __builtin_nontemporal_store(o, reinterpret_cast<fx4*>(out + ooff));

    if (!more) break;
    x = xn; ooff = ooff_n; s = s_next;
  }
}

// Generic fallback (R8 structure): 2 rows per block of dim/4 threads.
__global__ void tcfp_embedding_generic(const int* __restrict__ indices,
                                       const float* __restrict__ weight,
                                       float* __restrict__ out,
                                       int dim, int nrows) {
  __shared__ ix2 bins[64];
  const int tid = threadIdx.x;
  build_bins(bins, tid);
  __syncthreads();

  const int row0 = blockIdx.x * 2;
  const int row1 = row0 + 1;
  const int lane = tid & 63;
  const int col  = (tid >> 6) * 256 + lane * 4;
  const bool has1 = (row1 < nrows);

  const int w0 = indices[row0];
  const int w1 = has1 ? indices[row1] : w0;
  const fx4 x0 =
      *reinterpret_cast<const fx4*>(weight + (size_t)w0 * (size_t)dim + col);
  const fx4 x1 =
      *reinterpret_cast<const fx4*>(weight + (size_t)w1 * (size_t)dim + col);

  const fx4 o0 = tcfp12_quantize(x0, bins);
  const fx4 o1 = tcfp12_quantize(x1, bins);

  __builtin_nontemporal_store(
      o0, reinterpret_cast<fx4*>(out + (size_t)row0 * (size_t)dim + col));
  if (has1)
    __builtin_nontemporal_store(
        o1, reinterpret_cast<fx4*>(out + (size_t)row1 * (size_t)dim + col));
}

extern "C" void kernel_launch(void* const* d_in, const int* in_sizes, int n_in,
                              void* d_out, int out_size, void* d_ws, size_t ws_size,
                              hipStream_t stream) {
  const int*   indices = (const int*)d_in[0];
  const float* weight  = (const float*)d_in[1];
  float*       out     = (float*)d_out;

  const int nrows = in_sizes[0];          // 8*4096 = 32768
  const int dim   = out_size / nrows;     // 768

  if (dim == 768) {
    const int nstrips = nrows * 3;                   // 98304
    int grid = 2048;                                 // 8192 waves, 12 iters
    if (grid * 4 > nstrips) grid = (nstrips + 3) / 4;
    const int wave_stride = grid * 4;
    tcfp_embedding_768_persist<<<grid, 256, 0, stream>>>(indices, weight, out,
                                                         nstrips, wave_stride);
  } else {
    const int threads = dim / 4;
    const int grid = (nrows + 1) / 2;
    tcfp_embedding_generic<<<grid, threads, 0, stream>>>(indices, weight, out,
                                                         dim, nrows);
  }
}

// Round 11
// 35.276 us; speedup vs baseline: 1.1089x; 1.1089x over previous
//
#include <hip/hip_runtime.h>
#include <cstddef>

// ---------------------------------------------------------------------------
// TCFPEmbedding: out[i,:] = fake_quantize_tcfp12(weight[indices[i], :])
//   per 64-elem block: scale = max(min(absmax, 3*std), 1e-12)
//   q    = clip(rint(x/scale*127), -127, 127); main = q*(scale/127)
//   res  = x - main; rmax = max(absmax(res), 1e-12)
//   idx  = searchsorted(NF4_MIDPOINTS, res/rmax, side='left')  (strict mid < rn)
//   out  = main + NF4_LEVELS[idx]*rmax
// R8 structure (champion): 1 block (192 thr = 3 waves) per TWO rows of 768;
// lane -> float4; 16-lane group == 64-elem quant block; DPP row_ror
// reductions; 64-bin packed NF4 LUT (8B: exact f32 midpoint + i8 levels);
// NT stores. R11: both exact IEEE divides -> v_rcp_f32 (~1ulp; saves ~20
// VALU + ~18 serial chain cycles per chunk; rint-boundary flips bounded by
// one residual quantum ~2e-3 << 0.108 threshold). Bin table extended to 66
// entries (64/65 dup 63) so the j<=63 clamp is gone (rn <= 1+2e-7).
// ---------------------------------------------------------------------------

typedef float fx4 __attribute__((ext_vector_type(4)));
typedef int   ix2 __attribute__((ext_vector_type(2)));

namespace {

constexpr float kL[16] = {
    -1.0f, -0.6961928009986877f, -0.5250730514526367f, -0.39491748809814453f,
    -0.28444138169288635f, -0.18477343022823334f, -0.09105003625154495f, 0.0f,
    0.07958029955625534f, 0.16093020141124725f, 0.24611230194568634f,
    0.33791524171829224f, 0.44070982933044434f, 0.5626170039176941f,
    0.8481764793395996f, 1.0f};

} // namespace

__device__ __constant__ float kNF4Levels[16] = {
    -1.0f, -0.6961928009986877f, -0.5250730514526367f, -0.39491748809814453f,
    -0.28444138169288635f, -0.18477343022823334f, -0.09105003625154495f, 0.0f,
    0.07958029955625534f, 0.16093020141124725f, 0.24611230194568634f,
    0.33791524171829224f, 0.44070982933044434f, 0.5626170039176941f,
    0.8481764793395996f, 1.0f};

// DPP row rotate (within 16-lane row): ror1=0x121 ror2=0x122 ror4=0x124 ror8=0x128
template <int CTRL>
__device__ __forceinline__ float dpp_rorf(float v) {
  return __builtin_bit_cast(
      float, __builtin_amdgcn_update_dpp(0, __builtin_bit_cast(int, v), CTRL,
                                         0xF, 0xF, true));
}

__device__ __forceinline__ void build_bins(ix2* bins, int tid) {
  if (tid < 66) {
    const int j = (tid > 63) ? 63 : tid;             // entries 64/65 dup 63
    const float L = j * 0.03125f - 1.0f;             // bin left edge (exact)
    int base = 0;
#pragma unroll
    for (int k = 0; k < 15; ++k) {
      const float mid = (kL[k] + kL[k + 1]) * 0.5f;  // compile-time f32
      base += (mid < L) ? 1 : 0;                     // count(mid < L)
    }
    float mstar = 2.0f;                              // sentinel: never < rn
    float lo = kNF4Levels[base];
    float hi = lo;
    if (base < 15) {
      float mb = 0.0f;
#pragma unroll
      for (int k = 0; k < 15; ++k)
        if (k == base) mb = (kL[k] + kL[k + 1]) * 0.5f;
      if (mb < L + 0.03125f) {                       // midpoint inside bin
        mstar = mb;
        hi = kNF4Levels[base + 1];
      }
    }
    const int lo_i = (int)rintf(lo * 127.0f);        // [-127,127]
    const int hi_i = (int)rintf(hi * 127.0f);
    ix2 b;
    b.x = __builtin_bit_cast(int, mstar);
    b.y = (lo_i & 0xff) | ((hi_i & 0xff) << 8);
    bins[tid] = b;
  }
}

// Fake-quantize this thread's 4 elems (one 64-elem quant block per 16-lane
// group). `bins` = LDS 66-entry packed NF4 bin table (8B/entry).
__device__ __forceinline__ fx4 tcfp12_quantize(fx4 x, const ix2* bins) {
  // ---- block stats via DPP rotate-reduce over the 16-lane row ----
  float am = fmaxf(fmaxf(fabsf(x.x), fabsf(x.y)), fmaxf(fabsf(x.z), fabsf(x.w)));
  float s  = (x.x + x.y) + (x.z + x.w);
  float ss = fmaf(x.x, x.x, fmaf(x.y, x.y, fmaf(x.z, x.z, x.w * x.w)));
  am = fmaxf(am, dpp_rorf<0x121>(am)); s += dpp_rorf<0x121>(s); ss += dpp_rorf<0x121>(ss);
  am = fmaxf(am, dpp_rorf<0x122>(am)); s += dpp_rorf<0x122>(s); ss += dpp_rorf<0x122>(ss);
  am = fmaxf(am, dpp_rorf<0x124>(am)); s += dpp_rorf<0x124>(s); ss += dpp_rorf<0x124>(ss);
  am = fmaxf(am, dpp_rorf<0x128>(am)); s += dpp_rorf<0x128>(s); ss += dpp_rorf<0x128>(ss);

  const float mean  = s * 0.015625f;                       // /64
  const float var   = fmaxf(ss * 0.015625f - mean * mean, 0.0f);
  const float scale = fmaxf(fminf(am, 3.0f * sqrtf(var)), 1e-12f);
  const float to_q   = 127.0f * __builtin_amdgcn_rcpf(scale);  // ~1ulp
  const float from_q = scale * (1.0f / 127.0f);

  // ---- int8 main component (med3 = clamp) ----
  const float q0 = __builtin_amdgcn_fmed3f(rintf(x.x * to_q), -127.0f, 127.0f);
  const float q1 = __builtin_amdgcn_fmed3f(rintf(x.y * to_q), -127.0f, 127.0f);
  const float q2 = __builtin_amdgcn_fmed3f(rintf(x.z * to_q), -127.0f, 127.0f);
  const float q3 = __builtin_amdgcn_fmed3f(rintf(x.w * to_q), -127.0f, 127.0f);
  const float m0 = q0 * from_q, m1 = q1 * from_q, m2 = q2 * from_q, m3 = q3 * from_q;
  const float r0 = x.x - m0, r1 = x.y - m1, r2 = x.z - m2, r3 = x.w - m3;

  // ---- residual absmax over the block (DPP rotate-reduce) ----
  float rm = fmaxf(fmaxf(fabsf(r0), fabsf(r1)), fmaxf(fabsf(r2), fabsf(r3)));
  rm = fmaxf(rm, dpp_rorf<0x121>(rm));
  rm = fmaxf(rm, dpp_rorf<0x122>(rm));
  rm = fmaxf(rm, dpp_rorf<0x124>(rm));
  rm = fmaxf(rm, dpp_rorf<0x128>(rm));
  rm = fmaxf(rm, 1e-12f);
  const float invr = __builtin_amdgcn_rcpf(rm);  // ~1ulp
  const float rmq  = rm * (1.0f / 127.0f);       // level = i8/127 folded scale

  // ---- NF4 residual via packed LUT + combine ----
  fx4 o;
#pragma unroll
  for (int e = 0; e < 4; ++e) {
    const float r  = (e == 0) ? r0 : (e == 1) ? r1 : (e == 2) ? r2 : r3;
    const float mn = (e == 0) ? m0 : (e == 1) ? m1 : (e == 2) ? m2 : m3;
    const float rn = r * invr;                       // in [-1-eps, 1+eps]
    const float t  = fmaf(rn, 32.0f, 32.0f);         // [-3e-6, 64.0001]
    const int j = (int)t;                            // trunc: [-eps]->0, max 64
    const ix2 b = bins[j];                           // {mstar_f32, lo_i8|hi_i8<<8}
    const float mstar = __builtin_bit_cast(float, b.x);
    const int   off   = (rn > mstar) ? 8 : 0;        // strict: side='left'
    const int   li    = (int)((signed char)((b.y >> off) & 0xff));
    const float oe = fmaf((float)li, rmq, mn);
    if (e == 0) o.x = oe; else if (e == 1) o.y = oe;
    else if (e == 2) o.z = oe; else o.w = oe;
  }
  return o;
}

__global__ void __launch_bounds__(192)
tcfp_embedding_kernel(const int* __restrict__ indices,
                      const float* __restrict__ weight,
                      float* __restrict__ out,
                      int dim, int nrows) {
  __shared__ ix2 bins[66];  // packed NF4 bin table (66 entries: no clamp)
  const int tid = threadIdx.x;
  build_bins(bins, tid);
  __syncthreads();

  const int row0 = blockIdx.x * 2;
  const int row1 = row0 + 1;
  const int lane = tid & 63;
  const int col  = (tid >> 6) * 256 + lane * 4;  // chunk never straddles a row
  const bool has1 = (row1 < nrows);

  // Two independent gathers issued back-to-back (2x memory-level parallelism)
  const int w0 = indices[row0];                    // uniform -> scalar load
  const int w1 = has1 ? indices[row1] : w0;
  const fx4 x0 =
      *reinterpret_cast<const fx4*>(weight + (size_t)w0 * (size_t)dim + col);
  const fx4 x1 =
      *reinterpret_cast<const fx4*>(weight + (size_t)w1 * (size_t)dim + col);

  const fx4 o0 = tcfp12_quantize(x0, bins);
  const fx4 o1 = tcfp12_quantize(x1, bins);

  // Nontemporal: output is a write-once stream; don't evict weight from L2/L3
  __builtin_nontemporal_store(
      o0, reinterpret_cast<fx4*>(out + (size_t)row0 * (size_t)dim + col));
  if (has1)
    __builtin_nontemporal_store(
        o1, reinterpret_cast<fx4*>(out + (size_t)row1 * (size_t)dim + col));
}

extern "C" void kernel_launch(void* const* d_in, const int* in_sizes, int n_in,
                              void* d_out, int out_size, void* d_ws, size_t ws_size,
                              hipStream_t stream) {
  const int*   indices = (const int*)d_in[0];
  const float* weight  = (const float*)d_in[1];
  float*       out     = (float*)d_out;

  const int nrows = in_sizes[0];          // 8*4096 = 32768
  const int dim   = out_size / nrows;     // 768
  const int threads = dim / 4;            // 192 (3 waves; dim % 256 == 0)
  const int grid = (nrows + 1) / 2;       // 2 rows per block

  tcfp_embedding_kernel<<<grid, threads, 0, stream>>>(indices, weight, out,
                                                      dim, nrows);
}